// Round 13
// baseline (279.643 us; speedup 1.0000x reference)
//
#include <hip/hip_runtime.h>
#include <hip/hip_bf16.h>

typedef __bf16 bf16_t;
typedef __bf16 bf16x8 __attribute__((ext_vector_type(8)));
typedef __bf16 bf16x4 __attribute__((ext_vector_type(4)));
typedef float  f32x4  __attribute__((ext_vector_type(4)));

#define LDS_DST(p) ((__attribute__((address_space(3))) void*)(p))
#define GLB_SRC(p) ((const __attribute__((address_space(1))) void*)(p))

#define SBAR()   asm volatile("s_barrier" ::: "memory")
#define WVM3()   asm volatile("s_waitcnt vmcnt(3)" ::: "memory")
#define WVM1()   asm volatile("s_waitcnt vmcnt(1)" ::: "memory")
#define WVM0()   asm volatile("s_waitcnt vmcnt(0)" ::: "memory")
#define SP1()    __builtin_amdgcn_s_setprio(1)
#define SP0()    __builtin_amdgcn_s_setprio(0)

#define SLOT 24576   // A 8 KB @0 + B 16 KB @8192, x2 slots = 48 KB LDS

// ============== fp32 -> bf16 converts, one launch, 4x float4/thread ==========
__global__ void __launch_bounds__(256)
convert_kernel(const float* __restrict__ q_in, const float* __restrict__ v_in,
               const float* __restrict__ wq_in, const float* __restrict__ wk_in,
               const float* __restrict__ wv_in,
               bf16_t* __restrict__ qb, bf16_t* __restrict__ vb,
               bf16_t* __restrict__ wqb, bf16_t* __restrict__ wkb,
               bf16_t* __restrict__ wvb) {
  const int tid = threadIdx.x;
  int r = blockIdx.x;
  const float* in; bf16_t* out; int base;
  if (r < 6144) {
    in = (r < 3072) ? q_in : v_in;
    out = (r < 3072) ? qb : vb;
    base = (r % 3072) * 1024;
  } else {
    r -= 6144;
    in = (r < 144) ? wq_in : (r < 288 ? wk_in : wv_in);
    out = (r < 144) ? wqb : (r < 288 ? wkb : wvb);
    base = (r % 144) * 1024;
  }
#pragma unroll
  for (int j = 0; j < 4; ++j) {
    const int i = base + j * 256 + tid;
    const float4 v = reinterpret_cast<const float4*>(in)[i];
    bf16x4 o;
    o[0] = (bf16_t)v.x; o[1] = (bf16_t)v.y; o[2] = (bf16_t)v.z; o[3] = (bf16_t)v.w;
    reinterpret_cast<bf16x4*>(out)[i] = o;
  }
}

// ---------------- bf16 transpose: in [z][R][C] -> out [z][C][R] ----------------
__global__ void __launch_bounds__(256)
transpose_bf16_kernel(const bf16_t* __restrict__ in, bf16_t* __restrict__ out,
                      int R, int C) {
  __shared__ bf16_t tile[64][72];
  const long base = (long)blockIdx.z * R * C;
  const bf16_t* ib = in + base;
  bf16_t* ob = out + base;
  const int r0 = blockIdx.x * 64, c0 = blockIdx.y * 64;
  const int tid = threadIdx.x;
  const int rr = tid >> 3, cg = tid & 7;
#pragma unroll
  for (int p = 0; p < 2; ++p) {
    int row = p * 32 + rr;
    bf16x8 v = *reinterpret_cast<const bf16x8*>(ib + (long)(r0 + row) * C + c0 + cg * 8);
    *reinterpret_cast<bf16x8*>(&tile[row][cg * 8]) = v;
  }
  __syncthreads();
#pragma unroll
  for (int p = 0; p < 2; ++p) {
    int c = p * 32 + rr;
    bf16x8 v;
#pragma unroll
    for (int i = 0; i < 8; ++i) v[i] = tile[cg * 8 + i][c];
    *reinterpret_cast<bf16x8*>(ob + (long)(c0 + c) * R + r0 + cg * 8) = v;
  }
}

// ===== 128x256 GEMM, BK=32, 2 blocks/CU (48 KB LDS, <=128 VGPR), 2-phase =====
// R12 structure, R13 fix: prologue A staging used a stale pointer with a
// spurious wr*64 row offset (waves 4-7 staged rows 128..191 into tile0's
// lower half -> absmax 84). Single pointer pA now used everywhere.
// Schedule per tile t (slot t&1): frags af[4] (A), bf0[2] (B nh0), bfB[2] (B1);
// af/bf0 for tile t read at P_b(t-1), bfB at P_a(t).
//  P_a(t): read bfB=B1(t); stage A(t+2) [1 instr];
//          MFMA (af01,bf0)+(af01,bfB); WVM1; SBAR c1
//  P_b(t): MFMA (af23,bfB)+(af23,bf0);
//          read af=A(t+1), bf0=B0(t+1) [slot sn]; stage B(t+2) [2]; SBAR c2
// Hazards: stage A(t+2)@Pa(t) vs A(t+1) reads @Pb(t): c2(t-1)..c1(t) OK;
//   stage B(t+2)@Pb(t) vs B1(t)@Pa(t): c1(t) between OK.
// WVM1@c1(t): queue [A(t+1),B(t+1)x2,A(t+2)] -> confirms all but A(t+2),
//   exactly what P_b(t)/P_a(t+1) read. Prologue: 6 instrs, WVM3 = t0 landed.
// LDS swizzle (BK=32): store LDS[row][cg] from global cg^(row&3); read at
// cg = lg^(row&3) (involution, rule #21).

__device__ __forceinline__ void read_Af(const char* smem, int s, int aoff,
                                        bf16x8 (&af)[4]) {
#pragma unroll
  for (int mf = 0; mf < 4; ++mf)
    af[mf] = *reinterpret_cast<const bf16x8*>(smem + s + aoff + mf * 1024);
}

__device__ __forceinline__ void read_Bf(const char* smem, int s, int boff, int nh,
                                        bf16x8 (&bf_)[2]) {
#pragma unroll
  for (int nf = 0; nf < 2; ++nf)
    bf_[nf] = *reinterpret_cast<const bf16x8*>(
        smem + s + boff + nh * 2048 + nf * 1024);
}

template <int AH, int NH>
__device__ __forceinline__ void mfma_q(const bf16x8 (&af)[4], const bf16x8 (&bf_)[2],
                                       f32x4 (&acc)[4][4]) {
#pragma unroll
  for (int fi = 0; fi < 2; ++fi)
#pragma unroll
    for (int nf = 0; nf < 2; ++nf)
      acc[AH * 2 + fi][NH * 2 + nf] = __builtin_amdgcn_mfma_f32_16x16x32_bf16(
          af[AH * 2 + fi], bf_[nf], acc[AH * 2 + fi][NH * 2 + nf], 0, 0, 0);
}

#define STAGE_A(s, kt)                                                        \
  __builtin_amdgcn_global_load_lds(GLB_SRC(pA + (kt)),                        \
      LDS_DST(smem + (s) * SLOT + wave * 1024), 16, 0, 0)

#define STAGE_B(s, kt) do {                                                   \
  _Pragma("unroll") for (int j_ = 0; j_ < 2; ++j_)                            \
    __builtin_amdgcn_global_load_lds(GLB_SRC(pB + (long)j_ * 128 * K + (kt)), \
        LDS_DST(smem + (s) * SLOT + 8192 + j_ * 8192 + wave * 1024),          \
        16, 0, 0);                                                            \
} while (0)

// MODE 0: bf16 out = acc + bias[n] (z=1 alt pointers); MODE 1: bf16 out =
// mask ? sigmoid(acc) : 0 (int32 mask direct); MODE 2: f32 out = acc
template <int MODE>
__global__ void __launch_bounds__(512, 4)
gemm8p_kernel(const bf16_t* __restrict__ A, const bf16_t* __restrict__ B,
              const float* __restrict__ bias, const int* __restrict__ mask,
              void* __restrict__ Cout, int M, int N, int K,
              long sA, long sB, long sC, long sMask,
              const bf16_t* __restrict__ A2, const bf16_t* __restrict__ B2,
              const float* __restrict__ bias2, void* __restrict__ C2) {
  __shared__ __align__(1024) char smem[49152];

  // ---- bijective XCD chunking (m204) + L2-supertile decode ----
  const int gx = gridDim.x, gy = gridDim.y;
  int f0 = blockIdx.x + gx * (blockIdx.y + gy * blockIdx.z);
  const int nwg = gx * gy * (int)gridDim.z;
  const int q8 = nwg >> 3, r8 = nwg & 7;
  const int xcd = f0 & 7, idx = f0 >> 3;
  int f1 = (xcd < r8 ? xcd * (q8 + 1) : r8 * (q8 + 1) + (xcd - r8) * q8) + idx;
  int bxi, byi, bz;
  if constexpr (MODE == 1) {
    // supertile 8bx x 2by (A 1.5MB + B 0.75MB = 2.25MB < 4MiB L2/XCD)
    bxi = ((f1 >> 6) & 1) * 8 + (f1 & 7);
    byi = ((f1 >> 4) & 3) * 2 + ((f1 >> 3) & 1);
    bz = f1 >> 7;
  } else {
    // bx-major: B panel (weights / vpT) stays L2-resident
    bxi = f1 % gx;
    const int t_ = f1 / gx;
    byi = t_ % gy;
    bz = t_ / gy;
  }

  const bf16_t* Ab; const bf16_t* Bb;
  const float* biasp = bias; void* Cp = Cout;
  if constexpr (MODE == 0) {
    if (bz) { Ab = A2; Bb = B2; biasp = bias2; Cp = C2; }
    else    { Ab = A;  Bb = B; }
  } else {
    Ab = A + bz * sA; Bb = B + bz * sB;
  }
  const int bm = bxi * 128, bn = byi * 256;
  const int tid = threadIdx.x;
  const int wave = tid >> 6, lane = tid & 63;
  const int wr = wave >> 2, wc = wave & 3;
  const int l15 = lane & 15, lg = lane >> 4;
  const int NT = K >> 5;

  // staging bases: chunk = wave*64+lane -> row = wave*16 + (lane>>2),
  // src col-group = (lane&3) ^ (row&3)  [inverse of read swizzle]
  const int srow = wave * 16 + (lane >> 2);
  const int cgs = ((lane & 3) ^ ((lane >> 2) & 3)) * 8;
  const bf16_t* pA = Ab + (long)(bm + srow) * K + cgs;   // R13: single, correct
  const bf16_t* pB = Bb + (long)(bn + srow) * K + cgs;

  // ds_read offsets: row*64 + swizzled col-group
  const int xk = ((lg ^ (l15 & 3)) << 4);
  const int aoff = l15 * 64 + xk + wr * 4096;        // A rows: wr*64 + mf*16 + l15
  const int boff = 8192 + wc * 4096 + l15 * 64 + xk; // B rows: wc*64 + nh*32+nf*16+l15

  f32x4 acc[4][4] = {};
  bf16x8 af[4], bf0[2], bfB[2];

  // ---- prologue: stage t0 (3 instr) + t1 (3) ----
  STAGE_A(0, 0); STAGE_B(0, 0);
  STAGE_A(1, 32); STAGE_B(1, 32);
  WVM3();   // t0's 3 instrs landed (t1's 3 may linger)
  SBAR();
  read_Af(smem, 0, aoff, af);          // A(t0)
  read_Bf(smem, 0, boff, 0, bf0);      // B0(t0)

  for (int t = 0; t + 2 < NT; ++t) {
    const int so = (t & 1) * SLOT, sn = ((t + 1) & 1) * SLOT;
    const int si = t & 1;
    const int k2 = (t + 2) << 5;
    // ---- P_a ----
    read_Bf(smem, so, boff, 1, bfB);               // B1(t)
    STAGE_A(si, k2);                               // A(t+2)
    SP1(); mfma_q<0, 0>(af, bf0, acc); mfma_q<0, 1>(af, bfB, acc); SP0();
    WVM1(); SBAR();                                // c1
    // ---- P_b ----
    SP1(); mfma_q<1, 1>(af, bfB, acc); mfma_q<1, 0>(af, bf0, acc); SP0();
    read_Af(smem, sn, aoff, af);                   // A(t+1)
    read_Bf(smem, sn, boff, 0, bf0);               // B0(t+1)
    STAGE_B(si, k2);                               // B(t+2)
    SBAR();                                        // c2
  }

  // ---- drain: tiles NT-2, NT-1 ----
  {
    const int so = ((NT - 2) & 1) * SLOT, sn = ((NT - 1) & 1) * SLOT;
    read_Bf(smem, so, boff, 1, bfB);
    SP1(); mfma_q<0, 0>(af, bf0, acc); mfma_q<0, 1>(af, bfB, acc); SP0();
    WVM0(); SBAR();
    SP1(); mfma_q<1, 1>(af, bfB, acc); mfma_q<1, 0>(af, bf0, acc); SP0();
    read_Af(smem, sn, aoff, af);
    read_Bf(smem, sn, boff, 0, bf0);
    SBAR();
    read_Bf(smem, sn, boff, 1, bfB);
    SP1(); mfma_q<0, 0>(af, bf0, acc); mfma_q<0, 1>(af, bfB, acc); SP0();
    SP1(); mfma_q<1, 1>(af, bfB, acc); mfma_q<1, 0>(af, bf0, acc); SP0();
  }

  // ---- C-write: 4 rounds of 32 rows; eb 32 KB; mask prefetched (T14) ----
  // (fully unrolled: acc/mask indices compile-time -- rule #20)
  float* eb = (float*)smem;
  const int lrow = tid >> 4, t15 = tid & 15;
#pragma unroll
  for (int rd = 0; rd < 4; ++rd) {
    const long rowbase = (long)(bm + rd * 32 + lrow) * N + bn;
    int4 m4[4];
    if constexpr (MODE == 1) {
      const int* mrow = mask + bz * sMask + rowbase;
#pragma unroll
      for (int q = 0; q < 4; ++q)
        m4[q] = *reinterpret_cast<const int4*>(mrow + (q * 16 + t15) * 4);
    }
    __syncthreads();
    if (wr == (rd >> 1)) {
#pragma unroll
      for (int fi = 0; fi < 2; ++fi)
#pragma unroll
        for (int nf = 0; nf < 4; ++nf)
#pragma unroll
          for (int r = 0; r < 4; ++r) {
            const int rowl = fi * 16 + lg * 4 + r;
            eb[rowl * 256 + wc * 64 + nf * 16 + l15] = acc[(rd & 1) * 2 + fi][nf][r];
          }
    }
    __syncthreads();
#pragma unroll
    for (int q = 0; q < 4; ++q) {
      const int c4 = (q * 16 + t15) * 4;
      const f32x4 v = *reinterpret_cast<const f32x4*>(&eb[lrow * 256 + c4]);
      if constexpr (MODE == 1) {
        bf16x4 o;
        o[0] = (bf16_t)(m4[q].x ? __builtin_amdgcn_rcpf(1.f + __expf(-v[0])) : 0.f);
        o[1] = (bf16_t)(m4[q].y ? __builtin_amdgcn_rcpf(1.f + __expf(-v[1])) : 0.f);
        o[2] = (bf16_t)(m4[q].z ? __builtin_amdgcn_rcpf(1.f + __expf(-v[2])) : 0.f);
        o[3] = (bf16_t)(m4[q].w ? __builtin_amdgcn_rcpf(1.f + __expf(-v[3])) : 0.f);
        *reinterpret_cast<bf16x4*>((bf16_t*)Cp + bz * sC + rowbase + c4) = o;
      } else if constexpr (MODE == 0) {
        const f32x4 b4 = *reinterpret_cast<const f32x4*>(biasp + bn + c4);
        bf16x4 o;
        o[0] = (bf16_t)(v[0] + b4[0]); o[1] = (bf16_t)(v[1] + b4[1]);
        o[2] = (bf16_t)(v[2] + b4[2]); o[3] = (bf16_t)(v[3] + b4[3]);
        *reinterpret_cast<bf16x4*>((bf16_t*)Cp + bz * sC + rowbase + c4) = o;
      } else {
        *reinterpret_cast<f32x4*>((float*)Cp + bz * sC + rowbase + c4) = v;
      }
    }
  }
}

extern "C" void kernel_launch(void* const* d_in, const int* in_sizes, int n_in,
                              void* d_out, int out_size, void* d_ws, size_t ws_size,
                              hipStream_t stream) {
  const float* queries = (const float*)d_in[0];
  const float* values  = (const float*)d_in[1];
  const int*   mask    = (const int*)d_in[2];
  const float* Wq = (const float*)d_in[3];
  const float* bq = (const float*)d_in[4];
  const float* Wk = (const float*)d_in[5];
  const float* bk = (const float*)d_in[6];
  const float* Wv = (const float*)d_in[7];
  const float* bv = (const float*)d_in[8];

  // B=8, L=2048, D=768. Workspace layout (bytes):
  char* ws = (char*)d_ws;
  bf16_t* qb  = (bf16_t*)(ws + 0);          // queries bf16   25165824
  bf16_t* vb  = (bf16_t*)(ws + 25165824);   // values bf16    25165824
  bf16_t* wqb = (bf16_t*)(ws + 50331648);   // Wq bf16         1179648
  bf16_t* wkb = (bf16_t*)(ws + 51511296);   // Wk bf16         1179648
  bf16_t* wvb = (bf16_t*)(ws + 52690944);   // Wv bf16         1179648
  bf16_t* qp  = (bf16_t*)(ws + 53870592);   // q_proj         25165824
  bf16_t* vp  = (bf16_t*)(ws + 79036416);   // v_proj         25165824
  bf16_t* kp  = (bf16_t*)(ws + 104202240);  // k_proj         25165824
  bf16_t* vpT = (bf16_t*)(ws + 129368064);  // v_proj^T       25165824
  bf16_t* P   = (bf16_t*)(ws + 154533888);  // sigmoid scores 67108864
  // total: 221642752

  // converts (q, v, 3 weights) in one launch, 4 float4/thread
  convert_kernel<<<6576, 256, 0, stream>>>(queries, values, Wq, Wk, Wv,
                                           qb, vb, wqb, wkb, wvb);

  const dim3 blk2(512);

  // q-proj & v-proj batched: z=0 qb*Wq+bq->qp, z=1 vb*Wv+bv->vp
  gemm8p_kernel<0><<<dim3(128, 3, 2), blk2, 0, stream>>>(
      qb, wqb, bq, nullptr, qp, 16384, 768, 768, 0, 0, 0, 0,
      vb, wvb, bv, vp);
  // k-proj (faithful quirk: k = Linear_k(v_proj))
  gemm8p_kernel<0><<<dim3(128, 3, 1), blk2, 0, stream>>>(
      vp, wkb, bk, nullptr, kp, 16384, 768, 768, 0, 0, 0, 0,
      vp, wkb, bk, kp);

  // v_proj [b][2048][768] -> v_projT [b][768][2048]
  transpose_bf16_kernel<<<dim3(32, 12, 8), 256, 0, stream>>>(vp, vpT, 2048, 768);

  // P = sigmoid(mask(q k^T)) : per batch [2048,2048], K=768; int32 mask direct
  gemm8p_kernel<1><<<dim3(16, 8, 8), blk2, 0, stream>>>(
      qp, kp, nullptr, mask, P, 2048, 2048, 768,
      (long)2048 * 768, (long)2048 * 768, (long)2048 * 2048, (long)2048 * 2048,
      nullptr, nullptr, nullptr, nullptr);

  // context = P v : per batch [2048,768], K=2048, fp32 out
  gemm8p_kernel<2><<<dim3(16, 3, 8), blk2, 0, stream>>>(
      P, vpT, nullptr, nullptr, d_out, 2048, 768, 2048,
      (long)2048 * 2048, (long)768 * 2048, (long)2048 * 768, 0,
      nullptr, nullptr, nullptr, nullptr);
}

// Round 14
// 276.292 us; speedup vs baseline: 1.0121x; 1.0121x over previous
//
#include <hip/hip_runtime.h>
#include <hip/hip_bf16.h>

typedef __bf16 bf16_t;
typedef __bf16 bf16x8 __attribute__((ext_vector_type(8)));
typedef __bf16 bf16x4 __attribute__((ext_vector_type(4)));
typedef float  f32x4  __attribute__((ext_vector_type(4)));

#define LDS_DST(p) ((__attribute__((address_space(3))) void*)(p))
#define GLB_SRC(p) ((const __attribute__((address_space(1))) void*)(p))

#define SBAR()   asm volatile("s_barrier" ::: "memory")
#define WVM3()   asm volatile("s_waitcnt vmcnt(3)" ::: "memory")
#define WVM1()   asm volatile("s_waitcnt vmcnt(1)" ::: "memory")
#define WVM0()   asm volatile("s_waitcnt vmcnt(0)" ::: "memory")
#define SP1()    __builtin_amdgcn_s_setprio(1)
#define SP0()    __builtin_amdgcn_s_setprio(0)

#define SLOT 24576   // A 8 KB @0 + B 16 KB @8192, x2 slots = 48 KB LDS

// ============== fp32 -> bf16 converts, one launch, 4x float4/thread ==========
__global__ void __launch_bounds__(256)
convert_kernel(const float* __restrict__ q_in, const float* __restrict__ v_in,
               const float* __restrict__ wq_in, const float* __restrict__ wk_in,
               const float* __restrict__ wv_in,
               bf16_t* __restrict__ qb, bf16_t* __restrict__ vb,
               bf16_t* __restrict__ wqb, bf16_t* __restrict__ wkb,
               bf16_t* __restrict__ wvb) {
  const int tid = threadIdx.x;
  int r = blockIdx.x;
  const float* in; bf16_t* out; int base;
  if (r < 6144) {
    in = (r < 3072) ? q_in : v_in;
    out = (r < 3072) ? qb : vb;
    base = (r % 3072) * 1024;
  } else {
    r -= 6144;
    in = (r < 144) ? wq_in : (r < 288 ? wk_in : wv_in);
    out = (r < 144) ? wqb : (r < 288 ? wkb : wvb);
    base = (r % 144) * 1024;
  }
#pragma unroll
  for (int j = 0; j < 4; ++j) {
    const int i = base + j * 256 + tid;
    const float4 v = reinterpret_cast<const float4*>(in)[i];
    bf16x4 o;
    o[0] = (bf16_t)v.x; o[1] = (bf16_t)v.y; o[2] = (bf16_t)v.z; o[3] = (bf16_t)v.w;
    reinterpret_cast<bf16x4*>(out)[i] = o;
  }
}

// ---------------- bf16 transpose: in [z][R][C] -> out [z][C][R] ----------------
__global__ void __launch_bounds__(256)
transpose_bf16_kernel(const bf16_t* __restrict__ in, bf16_t* __restrict__ out,
                      int R, int C) {
  __shared__ bf16_t tile[64][72];
  const long base = (long)blockIdx.z * R * C;
  const bf16_t* ib = in + base;
  bf16_t* ob = out + base;
  const int r0 = blockIdx.x * 64, c0 = blockIdx.y * 64;
  const int tid = threadIdx.x;
  const int rr = tid >> 3, cg = tid & 7;
#pragma unroll
  for (int p = 0; p < 2; ++p) {
    int row = p * 32 + rr;
    bf16x8 v = *reinterpret_cast<const bf16x8*>(ib + (long)(r0 + row) * C + c0 + cg * 8);
    *reinterpret_cast<bf16x8*>(&tile[row][cg * 8]) = v;
  }
  __syncthreads();
#pragma unroll
  for (int p = 0; p < 2; ++p) {
    int c = p * 32 + rr;
    bf16x8 v;
#pragma unroll
    for (int i = 0; i < 8; ++i) v[i] = tile[cg * 8 + i][c];
    *reinterpret_cast<bf16x8*>(ob + (long)(c0 + c) * R + r0 + cg * 8) = v;
  }
}

// ===== 128x256 GEMM, BK=32, 2 blocks/CU (48 KB LDS, <=128 VGPR), 2-phase =====
// R14 fix: LDS swizzle now on (row>>1)&3, not row&3. With 64B rows, rows r and
// r+2 alias the same banks; row&3 left rows r/r+4 colliding -> 4-way conflict
// (R13: SQ_LDS_BANK_CONFLICT 7.34M, ~12us/dispatch). Granule index
// (4*row + cg) mod 8 with cg = lg ^ ((row>>1)&3) is distinct across any 8
// consecutive lanes -> conflict-free. Staging inverse: (srow>>1)&3 =
// (lane>>3)&3 (srow = wave*16 + lane>>2). Involution verified.
// Schedule per tile t (slot t&1): frags af[4] (A), bf0[2] (B nh0), bfB[2] (B1);
// af/bf0 for tile t read at P_b(t-1), bfB at P_a(t).
//  P_a(t): read bfB=B1(t); stage A(t+2) [1]; MFMA (af01,bf0)+(af01,bfB);
//          WVM1; SBAR c1
//  P_b(t): MFMA (af23,bfB)+(af23,bf0); read af=A(t+1), bf0=B0(t+1);
//          stage B(t+2) [2]; SBAR c2
// Hazard/vmcnt map as R13 (verified).

__device__ __forceinline__ void read_Af(const char* smem, int s, int aoff,
                                        bf16x8 (&af)[4]) {
#pragma unroll
  for (int mf = 0; mf < 4; ++mf)
    af[mf] = *reinterpret_cast<const bf16x8*>(smem + s + aoff + mf * 1024);
}

__device__ __forceinline__ void read_Bf(const char* smem, int s, int boff, int nh,
                                        bf16x8 (&bf_)[2]) {
#pragma unroll
  for (int nf = 0; nf < 2; ++nf)
    bf_[nf] = *reinterpret_cast<const bf16x8*>(
        smem + s + boff + nh * 2048 + nf * 1024);
}

template <int AH, int NH>
__device__ __forceinline__ void mfma_q(const bf16x8 (&af)[4], const bf16x8 (&bf_)[2],
                                       f32x4 (&acc)[4][4]) {
#pragma unroll
  for (int fi = 0; fi < 2; ++fi)
#pragma unroll
    for (int nf = 0; nf < 2; ++nf)
      acc[AH * 2 + fi][NH * 2 + nf] = __builtin_amdgcn_mfma_f32_16x16x32_bf16(
          af[AH * 2 + fi], bf_[nf], acc[AH * 2 + fi][NH * 2 + nf], 0, 0, 0);
}

#define STAGE_A(s, kt)                                                        \
  __builtin_amdgcn_global_load_lds(GLB_SRC(pA + (kt)),                        \
      LDS_DST(smem + (s) * SLOT + wave * 1024), 16, 0, 0)

#define STAGE_B(s, kt) do {                                                   \
  _Pragma("unroll") for (int j_ = 0; j_ < 2; ++j_)                            \
    __builtin_amdgcn_global_load_lds(GLB_SRC(pB + (long)j_ * 128 * K + (kt)), \
        LDS_DST(smem + (s) * SLOT + 8192 + j_ * 8192 + wave * 1024),          \
        16, 0, 0);                                                            \
} while (0)

// MODE 0: bf16 out = acc + bias[n] (z=1 alt pointers); MODE 1: bf16 out =
// mask ? sigmoid(acc) : 0 (int32 mask direct); MODE 2: f32 out = acc
template <int MODE>
__global__ void __launch_bounds__(512, 4)
gemm8p_kernel(const bf16_t* __restrict__ A, const bf16_t* __restrict__ B,
              const float* __restrict__ bias, const int* __restrict__ mask,
              void* __restrict__ Cout, int M, int N, int K,
              long sA, long sB, long sC, long sMask,
              const bf16_t* __restrict__ A2, const bf16_t* __restrict__ B2,
              const float* __restrict__ bias2, void* __restrict__ C2) {
  __shared__ __align__(1024) char smem[49152];

  // ---- bijective XCD chunking (m204) + L2-supertile decode ----
  const int gx = gridDim.x, gy = gridDim.y;
  int f0 = blockIdx.x + gx * (blockIdx.y + gy * blockIdx.z);
  const int nwg = gx * gy * (int)gridDim.z;
  const int q8 = nwg >> 3, r8 = nwg & 7;
  const int xcd = f0 & 7, idx = f0 >> 3;
  int f1 = (xcd < r8 ? xcd * (q8 + 1) : r8 * (q8 + 1) + (xcd - r8) * q8) + idx;
  int bxi, byi, bz;
  if constexpr (MODE == 1) {
    // supertile 8bx x 2by (A 1.5MB + B 0.75MB = 2.25MB < 4MiB L2/XCD)
    bxi = ((f1 >> 6) & 1) * 8 + (f1 & 7);
    byi = ((f1 >> 4) & 3) * 2 + ((f1 >> 3) & 1);
    bz = f1 >> 7;
  } else {
    // bx-major: B panel (weights / vpT) stays L2-resident
    bxi = f1 % gx;
    const int t_ = f1 / gx;
    byi = t_ % gy;
    bz = t_ / gy;
  }

  const bf16_t* Ab; const bf16_t* Bb;
  const float* biasp = bias; void* Cp = Cout;
  if constexpr (MODE == 0) {
    if (bz) { Ab = A2; Bb = B2; biasp = bias2; Cp = C2; }
    else    { Ab = A;  Bb = B; }
  } else {
    Ab = A + bz * sA; Bb = B + bz * sB;
  }
  const int bm = bxi * 128, bn = byi * 256;
  const int tid = threadIdx.x;
  const int wave = tid >> 6, lane = tid & 63;
  const int wr = wave >> 2, wc = wave & 3;
  const int l15 = lane & 15, lg = lane >> 4;
  const int NT = K >> 5;

  // staging bases: chunk = wave*64+lane -> row = wave*16 + (lane>>2),
  // src col-group = (lane&3) ^ ((row>>1)&3) = (lane&3) ^ ((lane>>3)&3)
  const int srow = wave * 16 + (lane >> 2);
  const int cgs = ((lane & 3) ^ ((lane >> 3) & 3)) * 8;
  const bf16_t* pA = Ab + (long)(bm + srow) * K + cgs;
  const bf16_t* pB = Bb + (long)(bn + srow) * K + cgs;

  // ds_read offsets: row*64 + swizzled col-group; row bits0-3 = l15 everywhere
  const int xk = ((lg ^ ((l15 >> 1) & 3)) << 4);
  const int aoff = l15 * 64 + xk + wr * 4096;        // A rows: wr*64 + mf*16 + l15
  const int boff = 8192 + wc * 4096 + l15 * 64 + xk; // B rows: wc*64 + nh*32+nf*16+l15

  f32x4 acc[4][4] = {};
  bf16x8 af[4], bf0[2], bfB[2];

  // ---- prologue: stage t0 (3 instr) + t1 (3) ----
  STAGE_A(0, 0); STAGE_B(0, 0);
  STAGE_A(1, 32); STAGE_B(1, 32);
  WVM3();   // t0's 3 instrs landed (t1's 3 may linger)
  SBAR();
  read_Af(smem, 0, aoff, af);          // A(t0)
  read_Bf(smem, 0, boff, 0, bf0);      // B0(t0)

  for (int t = 0; t + 2 < NT; ++t) {
    const int so = (t & 1) * SLOT, sn = ((t + 1) & 1) * SLOT;
    const int si = t & 1;
    const int k2 = (t + 2) << 5;
    // ---- P_a ----
    read_Bf(smem, so, boff, 1, bfB);               // B1(t)
    STAGE_A(si, k2);                               // A(t+2)
    SP1(); mfma_q<0, 0>(af, bf0, acc); mfma_q<0, 1>(af, bfB, acc); SP0();
    WVM1(); SBAR();                                // c1
    // ---- P_b ----
    SP1(); mfma_q<1, 1>(af, bfB, acc); mfma_q<1, 0>(af, bf0, acc); SP0();
    read_Af(smem, sn, aoff, af);                   // A(t+1)
    read_Bf(smem, sn, boff, 0, bf0);               // B0(t+1)
    STAGE_B(si, k2);                               // B(t+2)
    SBAR();                                        // c2
  }

  // ---- drain: tiles NT-2, NT-1 ----
  {
    const int so = ((NT - 2) & 1) * SLOT, sn = ((NT - 1) & 1) * SLOT;
    read_Bf(smem, so, boff, 1, bfB);
    SP1(); mfma_q<0, 0>(af, bf0, acc); mfma_q<0, 1>(af, bfB, acc); SP0();
    WVM0(); SBAR();
    SP1(); mfma_q<1, 1>(af, bfB, acc); mfma_q<1, 0>(af, bf0, acc); SP0();
    read_Af(smem, sn, aoff, af);
    read_Bf(smem, sn, boff, 0, bf0);
    SBAR();
    read_Bf(smem, sn, boff, 1, bfB);
    SP1(); mfma_q<0, 0>(af, bf0, acc); mfma_q<0, 1>(af, bfB, acc); SP0();
    SP1(); mfma_q<1, 1>(af, bfB, acc); mfma_q<1, 0>(af, bf0, acc); SP0();
  }

  // ---- C-write: 4 rounds of 32 rows; eb 32 KB; mask prefetched (T14) ----
  // (fully unrolled: acc/mask indices compile-time -- rule #20)
  float* eb = (float*)smem;
  const int lrow = tid >> 4, t15 = tid & 15;
#pragma unroll
  for (int rd = 0; rd < 4; ++rd) {
    const long rowbase = (long)(bm + rd * 32 + lrow) * N + bn;
    int4 m4[4];
    if constexpr (MODE == 1) {
      const int* mrow = mask + bz * sMask + rowbase;
#pragma unroll
      for (int q = 0; q < 4; ++q)
        m4[q] = *reinterpret_cast<const int4*>(mrow + (q * 16 + t15) * 4);
    }
    __syncthreads();
    if (wr == (rd >> 1)) {
#pragma unroll
      for (int fi = 0; fi < 2; ++fi)
#pragma unroll
        for (int nf = 0; nf < 4; ++nf)
#pragma unroll
          for (int r = 0; r < 4; ++r) {
            const int rowl = fi * 16 + lg * 4 + r;
            eb[rowl * 256 + wc * 64 + nf * 16 + l15] = acc[(rd & 1) * 2 + fi][nf][r];
          }
    }
    __syncthreads();
#pragma unroll
    for (int q = 0; q < 4; ++q) {
      const int c4 = (q * 16 + t15) * 4;
      const f32x4 v = *reinterpret_cast<const f32x4*>(&eb[lrow * 256 + c4]);
      if constexpr (MODE == 1) {
        bf16x4 o;
        o[0] = (bf16_t)(m4[q].x ? __builtin_amdgcn_rcpf(1.f + __expf(-v[0])) : 0.f);
        o[1] = (bf16_t)(m4[q].y ? __builtin_amdgcn_rcpf(1.f + __expf(-v[1])) : 0.f);
        o[2] = (bf16_t)(m4[q].z ? __builtin_amdgcn_rcpf(1.f + __expf(-v[2])) : 0.f);
        o[3] = (bf16_t)(m4[q].w ? __builtin_amdgcn_rcpf(1.f + __expf(-v[3])) : 0.f);
        *reinterpret_cast<bf16x4*>((bf16_t*)Cp + bz * sC + rowbase + c4) = o;
      } else if constexpr (MODE == 0) {
        const f32x4 b4 = *reinterpret_cast<const f32x4*>(biasp + bn + c4);
        bf16x4 o;
        o[0] = (bf16_t)(v[0] + b4[0]); o[1] = (bf16_t)(v[1] + b4[1]);
        o[2] = (bf16_t)(v[2] + b4[2]); o[3] = (bf16_t)(v[3] + b4[3]);
        *reinterpret_cast<bf16x4*>((bf16_t*)Cp + bz * sC + rowbase + c4) = o;
      } else {
        *reinterpret_cast<f32x4*>((float*)Cp + bz * sC + rowbase + c4) = v;
      }
    }
  }
}

extern "C" void kernel_launch(void* const* d_in, const int* in_sizes, int n_in,
                              void* d_out, int out_size, void* d_ws, size_t ws_size,
                              hipStream_t stream) {
  const float* queries = (const float*)d_in[0];
  const float* values  = (const float*)d_in[1];
  const int*   mask    = (const int*)d_in[2];
  const float* Wq = (const float*)d_in[3];
  const float* bq = (const float*)d_in[4];
  const float* Wk = (const float*)d_in[5];
  const float* bk = (const float*)d_in[6];
  const float* Wv = (const float*)d_in[7];
  const float* bv = (const float*)d_in[8];

  // B=8, L=2048, D=768. Workspace layout (bytes):
  char* ws = (char*)d_ws;
  bf16_t* qb  = (bf16_t*)(ws + 0);          // queries bf16   25165824
  bf16_t* vb  = (bf16_t*)(ws + 25165824);   // values bf16    25165824
  bf16_t* wqb = (bf16_t*)(ws + 50331648);   // Wq bf16         1179648
  bf16_t* wkb = (bf16_t*)(ws + 51511296);   // Wk bf16         1179648
  bf16_t* wvb = (bf16_t*)(ws + 52690944);   // Wv bf16         1179648
  bf16_t* qp  = (bf16_t*)(ws + 53870592);   // q_proj         25165824
  bf16_t* vp  = (bf16_t*)(ws + 79036416);   // v_proj         25165824
  bf16_t* kp  = (bf16_t*)(ws + 104202240);  // k_proj         25165824
  bf16_t* vpT = (bf16_t*)(ws + 129368064);  // v_proj^T       25165824
  bf16_t* P   = (bf16_t*)(ws + 154533888);  // sigmoid scores 67108864
  // total: 221642752

  // converts (q, v, 3 weights) in one launch, 4 float4/thread
  convert_kernel<<<6576, 256, 0, stream>>>(queries, values, Wq, Wk, Wv,
                                           qb, vb, wqb, wkb, wvb);

  const dim3 blk2(512);

  // q-proj & v-proj batched: z=0 qb*Wq+bq->qp, z=1 vb*Wv+bv->vp
  gemm8p_kernel<0><<<dim3(128, 3, 2), blk2, 0, stream>>>(
      qb, wqb, bq, nullptr, qp, 16384, 768, 768, 0, 0, 0, 0,
      vb, wvb, bv, vp);
  // k-proj (faithful quirk: k = Linear_k(v_proj))
  gemm8p_kernel<0><<<dim3(128, 3, 1), blk2, 0, stream>>>(
      vp, wkb, bk, nullptr, kp, 16384, 768, 768, 0, 0, 0, 0,
      vp, wkb, bk, kp);

  // v_proj [b][2048][768] -> v_projT [b][768][2048]
  transpose_bf16_kernel<<<dim3(32, 12, 8), 256, 0, stream>>>(vp, vpT, 2048, 768);

  // P = sigmoid(mask(q k^T)) : per batch [2048,2048], K=768; int32 mask direct
  gemm8p_kernel<1><<<dim3(16, 8, 8), blk2, 0, stream>>>(
      qp, kp, nullptr, mask, P, 2048, 2048, 768,
      (long)2048 * 768, (long)2048 * 768, (long)2048 * 2048, (long)2048 * 2048,
      nullptr, nullptr, nullptr, nullptr);

  // context = P v : per batch [2048,768], K=2048, fp32 out
  gemm8p_kernel<2><<<dim3(16, 3, 8), blk2, 0, stream>>>(
      P, vpT, nullptr, nullptr, d_out, 2048, 768, 2048,
      (long)2048 * 2048, (long)768 * 2048, (long)2048 * 768, 0,
      nullptr, nullptr, nullptr, nullptr);
}

// Round 16
// 261.704 us; speedup vs baseline: 1.0685x; 1.0557x over previous
//
#include <hip/hip_runtime.h>
#include <hip/hip_bf16.h>

typedef __bf16 bf16_t;
typedef __bf16 bf16x8 __attribute__((ext_vector_type(8)));
typedef __bf16 bf16x4 __attribute__((ext_vector_type(4)));
typedef float  f32x4  __attribute__((ext_vector_type(4)));

#define LDS_DST(p) ((__attribute__((address_space(3))) void*)(p))
#define GLB_SRC(p) ((const __attribute__((address_space(1))) void*)(p))

#define SBAR()   asm volatile("s_barrier" ::: "memory")
#define WVM8()   asm volatile("s_waitcnt vmcnt(8)" ::: "memory")
#define WVM4()   asm volatile("s_waitcnt vmcnt(4)" ::: "memory")
#define WVM0()   asm volatile("s_waitcnt vmcnt(0)" ::: "memory")
#define SP1()    __builtin_amdgcn_s_setprio(1)
#define SP0()    __builtin_amdgcn_s_setprio(0)

// ============== fp32 -> bf16 converts, one launch, 4x float4/thread ==========
__global__ void __launch_bounds__(256)
convert_kernel(const float* __restrict__ q_in, const float* __restrict__ v_in,
               const float* __restrict__ wq_in, const float* __restrict__ wk_in,
               const float* __restrict__ wv_in,
               bf16_t* __restrict__ qb, bf16_t* __restrict__ vb,
               bf16_t* __restrict__ wqb, bf16_t* __restrict__ wkb,
               bf16_t* __restrict__ wvb) {
  const int tid = threadIdx.x;
  int r = blockIdx.x;
  const float* in; bf16_t* out; int base;
  if (r < 6144) {
    in = (r < 3072) ? q_in : v_in;
    out = (r < 3072) ? qb : vb;
    base = (r % 3072) * 1024;
  } else {
    r -= 6144;
    in = (r < 144) ? wq_in : (r < 288 ? wk_in : wv_in);
    out = (r < 144) ? wqb : (r < 288 ? wkb : wvb);
    base = (r % 144) * 1024;
  }
#pragma unroll
  for (int j = 0; j < 4; ++j) {
    const int i = base + j * 256 + tid;
    const float4 v = reinterpret_cast<const float4*>(in)[i];
    bf16x4 o;
    o[0] = (bf16_t)v.x; o[1] = (bf16_t)v.y; o[2] = (bf16_t)v.z; o[3] = (bf16_t)v.w;
    reinterpret_cast<bf16x4*>(out)[i] = o;
  }
}

// ========== 256x256 GEMM (R11 base: 2 merged phases/K-tile, counted vmcnt) ===
// R16 fix of R15: transposed emission (vpT) now ADDS THE BIAS before the bf16
// convert (R15 stored raw pre-bias acc -> absmax 74.5; context error
// = sum_k attn*bv ~ O(40-80)). One scalar bias load per thread (colT fixed).
// MODE0 eb uses a 4-aligned column XOR swizzle (col ^ (row&7)<<2): preserves
// f32x4 contiguity for row-wise emission and makes the column-wise transposed
// read 2-way banked. Standalone transpose kernel deleted.
// REGISTER BUDGET (hard limit, learned R6): acc 128 AGPR + <=16 live frags in
// main loop; epilogue reuses freed frag regs (mask 2x32 VGPR / tv 16 VGPR ok).

__device__ __forceinline__ void read_A(const char* smem, int off, bf16x8 (&af)[8], int xk0) {
#pragma unroll
  for (int mf = 0; mf < 4; ++mf)
#pragma unroll
    for (int kk = 0; kk < 2; ++kk)
      af[mf * 2 + kk] = *reinterpret_cast<const bf16x8*>(
          smem + off + mf * 2048 + (kk ? (xk0 ^ 64) : xk0));
}

__device__ __forceinline__ void read_B(const char* smem, int off, bf16x8 (&bf_)[4], int xk0) {
#pragma unroll
  for (int nf = 0; nf < 2; ++nf)
#pragma unroll
    for (int kk = 0; kk < 2; ++kk)
      bf_[nf * 2 + kk] = *reinterpret_cast<const bf16x8*>(
          smem + off + nf * 2048 + (kk ? (xk0 ^ 64) : xk0));
}

template <int MH, int NH>
__device__ __forceinline__ void mfma_q(const bf16x8 (&af)[8], const bf16x8 (&bf_)[4],
                                       f32x4 (&acc)[8][4]) {
#pragma unroll
  for (int mf = 0; mf < 4; ++mf)
#pragma unroll
    for (int nf = 0; nf < 2; ++nf)
#pragma unroll
      for (int kk = 0; kk < 2; ++kk)
        acc[MH * 4 + mf][NH * 2 + nf] = __builtin_amdgcn_mfma_f32_16x16x32_bf16(
            af[mf * 2 + kk], bf_[nf * 2 + kk], acc[MH * 4 + mf][NH * 2 + nf], 0, 0, 0);
}

#define STAGE_A(slot, mh, kt) do {                                            \
  _Pragma("unroll") for (int j_ = 0; j_ < 2; ++j_)                            \
    __builtin_amdgcn_global_load_lds(                                         \
        GLB_SRC(pA + (long)(j_ * 128 + (mh) * 64) * K + (kt)),                \
        LDS_DST(smem + (slot) * 65536 + (arow0 + j_ * 128 + (mh) * 64) * 128),\
        16, 0, 0);                                                            \
} while (0)

#define STAGE_B(slot, nh, kt) do {                                            \
  _Pragma("unroll") for (int j_ = 0; j_ < 2; ++j_)                            \
    __builtin_amdgcn_global_load_lds(                                         \
        GLB_SRC(pB + (long)(j_ * 128 + (nh) * 32) * K + (kt)),                \
        LDS_DST(smem + (slot) * 65536 + 32768 +                               \
                (brow0 + j_ * 128 + (nh) * 32) * 128),                        \
        16, 0, 0);                                                            \
} while (0)

// write acc round RD into chunk buffer eb (64 rows x 256 cols), plain cols
#define EWRITE(RD, eb) do {                                                   \
  _Pragma("unroll") for (int fi = 0; fi < 2; ++fi)                            \
  _Pragma("unroll") for (int nf = 0; nf < 4; ++nf)                            \
  _Pragma("unroll") for (int r = 0; r < 4; ++r) {                             \
    const int lr2 = wr * 32 + fi * 16 + lg * 4 + r;                           \
    (eb)[lr2 * 256 + wc * 64 + nf * 16 + l15] = acc[(RD) * 2 + fi][nf][r];    \
  }                                                                           \
} while (0)

// MODE0 variant: 4-aligned column XOR swizzle (enables transposed read)
#define EWRITE_S(RD, eb) do {                                                 \
  _Pragma("unroll") for (int fi = 0; fi < 2; ++fi)                            \
  _Pragma("unroll") for (int nf = 0; nf < 4; ++nf)                            \
  _Pragma("unroll") for (int r = 0; r < 4; ++r) {                             \
    const int lr2 = wr * 32 + fi * 16 + lg * 4 + r;                           \
    const int cS = (wc * 64 + nf * 16 + l15) ^ ((lr2 & 7) << 2);              \
    (eb)[lr2 * 256 + cS] = acc[(RD) * 2 + fi][nf][r];                         \
  }                                                                           \
} while (0)

// MODE 0: bf16 out = acc + bias[n] (z=1 alt pointers; also emits Ct = C^T
//         per batch if Ct != null, WITH bias). MODE 1: mask ? sigmoid : 0.
// MODE 2: f32 out = acc
template <int MODE>
__global__ void __launch_bounds__(512, 2)
gemm8p_kernel(const bf16_t* __restrict__ A, const bf16_t* __restrict__ B,
              const float* __restrict__ bias, const int* __restrict__ mask,
              void* __restrict__ Cout, int M, int N, int K,
              long sA, long sB, long sC, long sMask,
              const bf16_t* __restrict__ A2, const bf16_t* __restrict__ B2,
              const float* __restrict__ bias2, void* __restrict__ C2,
              bf16_t* __restrict__ Ct) {
  __shared__ __align__(1024) char smem[131072];

  // ---- bijective XCD chunking (m204) + supertile decode (R9) ----
  const int gx = gridDim.x, gy = gridDim.y;
  int f0 = blockIdx.x + gx * (blockIdx.y + gy * blockIdx.z);
  const int nwg = gx * gy * (int)gridDim.z;
  const int q8 = nwg >> 3, r8 = nwg & 7;
  const int xcd = f0 & 7, idx = f0 >> 3;
  int f1 = (xcd < r8 ? xcd * (q8 + 1) : r8 * (q8 + 1) + (xcd - r8) * q8) + idx;
  int bxi, byi, bz;
  if constexpr (MODE == 1) {
    // supertile = 8bx x 2by; f1 = bx + 8*(by&1) + 16*((by>>1) + 4*bz)
    bxi = f1 & 7;
    const int byL = (f1 >> 3) & 1;
    const int st = (f1 >> 4) & 3;
    bz = f1 >> 6;
    byi = st * 2 + byL;
  } else {
    // by-major: f1 = by + gy*(bx + gx*bz)
    byi = f1 % gy;
    const int t = f1 / gy;
    bxi = t % gx;
    bz = t / gx;
  }

  const bf16_t* Ab; const bf16_t* Bb;
  const float* biasp = bias; void* Cp = Cout;
  if constexpr (MODE == 0) {
    if (bz) { Ab = A2; Bb = B2; biasp = bias2; Cp = C2; }
    else    { Ab = A;  Bb = B; }
  } else {
    Ab = A + bz * sA; Bb = B + bz * sB;
  }
  const int bm = bxi * 256, bn = byi * 256;
  const int tid = threadIdx.x;
  const int wave = tid >> 6, lane = tid & 63;
  const int wr = wave >> 2, wc = wave & 3;
  const int l15 = lane & 15, lg = lane >> 4;
  const int xk0 = (lg * 16) ^ ((lane & 7) << 4);
  const int NT = K >> 6;

  // staging bases
  const int lr = lane >> 3;
  const int cgs = ((lane & 7) ^ lr) * 8;
  const int arow0 = wave * 8;
  const int brow0 = (wave >> 2) * 64 + (wave & 3) * 8;
  const bf16_t* pA = Ab + (long)(bm + arow0 + lr) * K + cgs;
  const bf16_t* pB = Bb + (long)(bn + brow0 + lr) * K + cgs;

  // ds_read base offsets
  const int aoff = wr * 16384 + l15 * 128;          // + slot*65536 + mh*8192
  const int boff = 32768 + wc * 8192 + l15 * 128;   // + slot*65536 + nh*4096

  f32x4 acc[8][4] = {};
  bf16x8 afX[8], bfB[4], bf0[4];

  // ---- prologue: t0 full (8 instrs), then A0/B0(1) (4), B1/A1(1) (4) ----
  STAGE_A(0, 0, 0); STAGE_B(0, 0, 0); STAGE_B(0, 1, 0); STAGE_A(0, 1, 0);
  STAGE_A(1, 0, 64); STAGE_B(1, 0, 64);
  STAGE_B(1, 1, 64); STAGE_A(1, 1, 64);
  WVM8();   // tile0's 8 instrs landed
  SBAR();
  read_A(smem, aoff + 0, afX, xk0);   // A0(t0)
  read_B(smem, boff + 0, bf0, xk0);   // B0(t0)

  int slot = 0;
  for (int t = 0; t + 2 < NT; ++t) {
    const int so = slot * 65536, sn = (slot ^ 1) * 65536;
    const int k2 = (t + 2) << 6;
    // ---- P_a ----
    read_B(smem, so + boff + 4096, bfB, xk0);        // B1(t)
    STAGE_A(slot, 0, k2); STAGE_B(slot, 0, k2);      // A0(t+2), B0(t+2)
    SP1(); mfma_q<0, 0>(afX, bf0, acc); SP0();
    SP1(); mfma_q<0, 1>(afX, bfB, acc); SP0();
    read_A(smem, so + aoff + 8192, afX, xk0);        // A1(t)
    WVM8(); SBAR();                                  // c1
    // ---- P_b ----
    SP1(); mfma_q<1, 1>(afX, bfB, acc); SP0();
    SP1(); mfma_q<1, 0>(afX, bf0, acc); SP0();
    read_A(smem, sn + aoff + 0, afX, xk0);           // A0(t+1)
    read_B(smem, sn + boff + 0, bf0, xk0);           // B0(t+1)
    STAGE_B(slot, 1, k2); STAGE_A(slot, 1, k2);      // B1(t+2), A1(t+2)
    WVM8(); SBAR();                                  // c2
    slot ^= 1;
  }

  // ---- drain: tiles NT-2 (so), NT-1 (sn); no staging ----
  {
    const int so = slot * 65536, sn = (slot ^ 1) * 65536;
    read_B(smem, so + boff + 4096, bfB, xk0);        // B1(NT-2)
    SP1(); mfma_q<0, 0>(afX, bf0, acc); SP0();
    SP1(); mfma_q<0, 1>(afX, bfB, acc); SP0();
    read_A(smem, so + aoff + 8192, afX, xk0);        // A1(NT-2)
    WVM4(); SBAR();
    SP1(); mfma_q<1, 1>(afX, bfB, acc); SP0();
    SP1(); mfma_q<1, 0>(afX, bf0, acc); SP0();
    read_A(smem, sn + aoff + 0, afX, xk0);           // A0(NT-1)
    read_B(smem, sn + boff + 0, bf0, xk0);           // B0(NT-1)
    WVM0(); SBAR();
    // last tile
    read_B(smem, sn + boff + 4096, bfB, xk0);        // B1(NT-1)
    SP1(); mfma_q<0, 0>(afX, bf0, acc); SP0();
    SP1(); mfma_q<0, 1>(afX, bfB, acc); SP0();
    read_A(smem, sn + aoff + 8192, afX, xk0);        // A1(NT-1)
    SP1(); mfma_q<1, 1>(afX, bfB, acc); SP0();
    SP1(); mfma_q<1, 0>(afX, bf0, acc); SP0();
  }

  // ---- C-write: 4 rounds, double-buffered 64KB chunks, 1 barrier/round ----
  // (fully unrolled: acc/mask/tv indices compile-time -- rule #20)
  float* eb0 = (float*)smem;
  float* eb1 = (float*)(smem + 65536);
  const int lrow = tid >> 3, t7 = tid & 7;
  const int growt0 = lrow + ((lrow >> 5) * 96);      // row map (wr0|wr1 halves)
  const bool doT = (MODE == 0) && (bz != 0) && (Ct != nullptr);
  int4 m4a[8], m4b[8];
  if constexpr (MODE == 1) {
    const int* mrow = mask + bz * sMask + (long)(bm + growt0) * N + bn;
#pragma unroll
    for (int q = 0; q < 8; ++q)
      m4a[q] = *reinterpret_cast<const int4*>(mrow + (q * 8 + t7) * 4);
  }
  if constexpr (MODE == 0) { EWRITE_S(0, eb0); } else { EWRITE(0, eb0); }
  __syncthreads();
#pragma unroll
  for (int rd = 0; rd < 4; ++rd) {
    // prefetch next round's mask (uses the buffer NOT consumed this round)
    if constexpr (MODE == 1) {
      if (rd < 3) {
        const int* mrow =
            mask + bz * sMask + (long)(bm + (rd + 1) * 32 + growt0) * N + bn;
        if ((rd & 1) == 0) {
#pragma unroll
          for (int q = 0; q < 8; ++q)
            m4b[q] = *reinterpret_cast<const int4*>(mrow + (q * 8 + t7) * 4);
        } else {
#pragma unroll
          for (int q = 0; q < 8; ++q)
            m4a[q] = *reinterpret_cast<const int4*>(mrow + (q * 8 + t7) * 4);
        }
      }
    }
    // stage next round's acc into the other buffer (overlaps with emission)
    if (rd < 3) {
      if constexpr (MODE == 0) {
        if ((rd & 1) == 0) { EWRITE_S(rd + 1, eb1); } else { EWRITE_S(rd + 1, eb0); }
      } else {
        if ((rd & 1) == 0) { EWRITE(rd + 1, eb1); } else { EWRITE(rd + 1, eb0); }
      }
    }
    // emit this round from its buffer
    const float* eb = ((rd & 1) == 0) ? eb0 : eb1;
    const long rowbase = (long)(bm + rd * 32 + growt0) * N + bn;
#pragma unroll
    for (int q = 0; q < 8; ++q) {
      const int c4 = (q * 8 + t7) * 4;
      const int cR = (MODE == 0) ? (c4 ^ ((lrow & 7) << 2)) : c4;
      const f32x4 v = *reinterpret_cast<const f32x4*>(&eb[lrow * 256 + cR]);
      if constexpr (MODE == 1) {
        const int4 mq = ((rd & 1) == 0) ? m4a[q] : m4b[q];
        bf16x4 o;
        o[0] = (bf16_t)(mq.x ? __builtin_amdgcn_rcpf(1.f + __expf(-v[0])) : 0.f);
        o[1] = (bf16_t)(mq.y ? __builtin_amdgcn_rcpf(1.f + __expf(-v[1])) : 0.f);
        o[2] = (bf16_t)(mq.z ? __builtin_amdgcn_rcpf(1.f + __expf(-v[2])) : 0.f);
        o[3] = (bf16_t)(mq.w ? __builtin_amdgcn_rcpf(1.f + __expf(-v[3])) : 0.f);
        *reinterpret_cast<bf16x4*>((bf16_t*)Cp + bz * sC + rowbase + c4) = o;
      } else if constexpr (MODE == 0) {
        const f32x4 b4 = *reinterpret_cast<const f32x4*>(biasp + bn + c4);
        bf16x4 o;
        o[0] = (bf16_t)(v[0] + b4[0]); o[1] = (bf16_t)(v[1] + b4[1]);
        o[2] = (bf16_t)(v[2] + b4[2]); o[3] = (bf16_t)(v[3] + b4[3]);
        *reinterpret_cast<bf16x4*>((bf16_t*)Cp + bz * sC + rowbase + c4) = o;
      } else {
        *reinterpret_cast<f32x4*>((float*)Cp + bz * sC + rowbase + c4) = v;
      }
    }
    // transposed emission (v-proj only): value(row rc, col c) lives at
    // eb[rc*256 + (c ^ ((rc&7)<<2))]; chunk row rc = g*32+r maps to in-batch
    // m = bm%2048 + g*128 + rd*32 + r. 64B contiguous per thread.
    // R16: bias ADDED here (colT is this thread's output column).
    if constexpr (MODE == 0) {
      if (doT) {
        const int colT = tid & 255, g = tid >> 8;
        const float bT = biasp[bn + colT];
        bf16_t tv[32];
#pragma unroll
        for (int r = 0; r < 32; ++r)
          tv[r] = (bf16_t)(eb[(g * 32 + r) * 256 + (colT ^ ((r & 7) << 2))] + bT);
        bf16_t* dst = Ct + (long)(bm >> 11) * (768L * 2048)
                      + (long)(bn + colT) * 2048
                      + (bm & 2047) + g * 128 + rd * 32;
#pragma unroll
        for (int j = 0; j < 4; ++j)
          *reinterpret_cast<bf16x8*>(dst + j * 8) =
              *reinterpret_cast<const bf16x8*>(&tv[j * 8]);
      }
    }
    __syncthreads();   // protects: reads of this buffer done before rd+2 write
  }
}

extern "C" void kernel_launch(void* const* d_in, const int* in_sizes, int n_in,
                              void* d_out, int out_size, void* d_ws, size_t ws_size,
                              hipStream_t stream) {
  const float* queries = (const float*)d_in[0];
  const float* values  = (const float*)d_in[1];
  const int*   mask    = (const int*)d_in[2];
  const float* Wq = (const float*)d_in[3];
  const float* bq = (const float*)d_in[4];
  const float* Wk = (const float*)d_in[5];
  const float* bk = (const float*)d_in[6];
  const float* Wv = (const float*)d_in[7];
  const float* bv = (const float*)d_in[8];

  // B=8, L=2048, D=768. Workspace layout (bytes):
  char* ws = (char*)d_ws;
  bf16_t* qb  = (bf16_t*)(ws + 0);          // queries bf16   25165824
  bf16_t* vb  = (bf16_t*)(ws + 25165824);   // values bf16    25165824
  bf16_t* wqb = (bf16_t*)(ws + 50331648);   // Wq bf16         1179648
  bf16_t* wkb = (bf16_t*)(ws + 51511296);   // Wk bf16         1179648
  bf16_t* wvb = (bf16_t*)(ws + 52690944);   // Wv bf16         1179648
  bf16_t* qp  = (bf16_t*)(ws + 53870592);   // q_proj         25165824
  bf16_t* vp  = (bf16_t*)(ws + 79036416);   // v_proj         25165824
  bf16_t* kp  = (bf16_t*)(ws + 104202240);  // k_proj         25165824
  bf16_t* vpT = (bf16_t*)(ws + 129368064);  // v_proj^T       25165824
  bf16_t* P   = (bf16_t*)(ws + 154533888);  // sigmoid scores 67108864
  // total: 221642752

  // converts (q, v, 3 weights) in one launch, 4 float4/thread
  convert_kernel<<<6576, 256, 0, stream>>>(queries, values, Wq, Wk, Wv,
                                           qb, vb, wqb, wkb, wvb);

  const dim3 blk2(512);

  // q-proj & v-proj batched: z=0 qb*Wq+bq->qp, z=1 vb*Wv+bv->vp (+vpT fused)
  gemm8p_kernel<0><<<dim3(64, 3, 2), blk2, 0, stream>>>(
      qb, wqb, bq, nullptr, qp, 16384, 768, 768, 0, 0, 0, 0,
      vb, wvb, bv, vp, vpT);
  // k-proj (faithful quirk: k = Linear_k(v_proj))
  gemm8p_kernel<0><<<dim3(64, 3, 1), blk2, 0, stream>>>(
      vp, wkb, bk, nullptr, kp, 16384, 768, 768, 0, 0, 0, 0,
      vp, wkb, bk, kp, nullptr);

  // P = sigmoid(mask(q k^T)) : per batch [2048,2048], K=768; int32 mask direct
  gemm8p_kernel<1><<<dim3(8, 8, 8), blk2, 0, stream>>>(
      qp, kp, nullptr, mask, P, 2048, 2048, 768,
      (long)2048 * 768, (long)2048 * 768, (long)2048 * 2048, (long)2048 * 2048,
      nullptr, nullptr, nullptr, nullptr, nullptr);

  // context = P v : per batch [2048,768], K=2048, fp32 out
  gemm8p_kernel<2><<<dim3(8, 3, 8), blk2, 0, stream>>>(
      P, vpT, nullptr, nullptr, d_out, 2048, 768, 2048,
      (long)2048 * 2048, (long)768 * 2048, (long)2048 * 768, 0,
      nullptr, nullptr, nullptr, nullptr, nullptr);
}

// Round 17
// 253.364 us; speedup vs baseline: 1.1037x; 1.0329x over previous
//
#include <hip/hip_runtime.h>
#include <hip/hip_bf16.h>

typedef __bf16 bf16_t;
typedef __bf16 bf16x8 __attribute__((ext_vector_type(8)));
typedef __bf16 bf16x4 __attribute__((ext_vector_type(4)));
typedef float  f32x4  __attribute__((ext_vector_type(4)));

#define LDS_DST(p) ((__attribute__((address_space(3))) void*)(p))
#define GLB_SRC(p) ((const __attribute__((address_space(1))) void*)(p))

#define SBAR()   asm volatile("s_barrier" ::: "memory")
#define WVM8()   asm volatile("s_waitcnt vmcnt(8)" ::: "memory")
#define WVM4()   asm volatile("s_waitcnt vmcnt(4)" ::: "memory")
#define WVM0()   asm volatile("s_waitcnt vmcnt(0)" ::: "memory")
#define SP1()    __builtin_amdgcn_s_setprio(1)
#define SP0()    __builtin_amdgcn_s_setprio(0)

// ============== fp32 -> bf16 converts, one launch, 4x float4/thread ==========
// flat ranges: [0,3072) q | [+3072) v | [+144) Wq | [+144) Wk | [+144) Wv
__global__ void __launch_bounds__(256)
convert_kernel(const float* __restrict__ q_in, const float* __restrict__ v_in,
               const float* __restrict__ wq_in, const float* __restrict__ wk_in,
               const float* __restrict__ wv_in,
               bf16_t* __restrict__ qb, bf16_t* __restrict__ vb,
               bf16_t* __restrict__ wqb, bf16_t* __restrict__ wkb,
               bf16_t* __restrict__ wvb) {
  const int tid = threadIdx.x;
  int r = blockIdx.x;
  const float* in; bf16_t* out; int base;
  if (r < 6144) {
    in = (r < 3072) ? q_in : v_in;
    out = (r < 3072) ? qb : vb;
    base = (r % 3072) * 1024;
  } else {
    r -= 6144;
    in = (r < 144) ? wq_in : (r < 288 ? wk_in : wv_in);
    out = (r < 144) ? wqb : (r < 288 ? wkb : wvb);
    base = (r % 144) * 1024;
  }
#pragma unroll
  for (int j = 0; j < 4; ++j) {
    const int i = base + j * 256 + tid;
    const float4 v = reinterpret_cast<const float4*>(in)[i];
    bf16x4 o;
    o[0] = (bf16_t)v.x; o[1] = (bf16_t)v.y; o[2] = (bf16_t)v.z; o[3] = (bf16_t)v.w;
    reinterpret_cast<bf16x4*>(out)[i] = o;
  }
}

// ---------------- bf16 transpose: in [z][R][C] -> out [z][C][R] ----------------
__global__ void __launch_bounds__(256)
transpose_bf16_kernel(const bf16_t* __restrict__ in, bf16_t* __restrict__ out,
                      int R, int C) {
  __shared__ bf16_t tile[64][72];
  const long base = (long)blockIdx.z * R * C;
  const bf16_t* ib = in + base;
  bf16_t* ob = out + base;
  const int r0 = blockIdx.x * 64, c0 = blockIdx.y * 64;
  const int tid = threadIdx.x;
  const int rr = tid >> 3, cg = tid & 7;
#pragma unroll
  for (int p = 0; p < 2; ++p) {
    int row = p * 32 + rr;
    bf16x8 v = *reinterpret_cast<const bf16x8*>(ib + (long)(r0 + row) * C + c0 + cg * 8);
    *reinterpret_cast<bf16x8*>(&tile[row][cg * 8]) = v;
  }
  __syncthreads();
#pragma unroll
  for (int p = 0; p < 2; ++p) {
    int c = p * 32 + rr;
    bf16x8 v;
#pragma unroll
    for (int i = 0; i < 8; ++i) v[i] = tile[cg * 8 + i][c];
    *reinterpret_cast<bf16x8*>(ob + (long)(c0 + c) * R + r0 + cg * 8) = v;
  }
}

// ========== 256x256 GEMM, 2 merged phases per K-tile, counted vmcnt ==========
// (R11 configuration -- best measured, 253.6us. Hazard map: see R7 notes.)
// REGISTER BUDGET (hard limit, learned R6): acc 128 AGPR + <=16 live frags in
// main loop; epilogue reuses freed frag regs (2x32 VGPR mask buffers ok).

__device__ __forceinline__ void read_A(const char* smem, int off, bf16x8 (&af)[8], int xk0) {
#pragma unroll
  for (int mf = 0; mf < 4; ++mf)
#pragma unroll
    for (int kk = 0; kk < 2; ++kk)
      af[mf * 2 + kk] = *reinterpret_cast<const bf16x8*>(
          smem + off + mf * 2048 + (kk ? (xk0 ^ 64) : xk0));
}

__device__ __forceinline__ void read_B(const char* smem, int off, bf16x8 (&bf_)[4], int xk0) {
#pragma unroll
  for (int nf = 0; nf < 2; ++nf)
#pragma unroll
    for (int kk = 0; kk < 2; ++kk)
      bf_[nf * 2 + kk] = *reinterpret_cast<const bf16x8*>(
          smem + off + nf * 2048 + (kk ? (xk0 ^ 64) : xk0));
}

template <int MH, int NH>
__device__ __forceinline__ void mfma_q(const bf16x8 (&af)[8], const bf16x8 (&bf_)[4],
                                       f32x4 (&acc)[8][4]) {
#pragma unroll
  for (int mf = 0; mf < 4; ++mf)
#pragma unroll
    for (int nf = 0; nf < 2; ++nf)
#pragma unroll
      for (int kk = 0; kk < 2; ++kk)
        acc[MH * 4 + mf][NH * 2 + nf] = __builtin_amdgcn_mfma_f32_16x16x32_bf16(
            af[mf * 2 + kk], bf_[nf * 2 + kk], acc[MH * 4 + mf][NH * 2 + nf], 0, 0, 0);
}

#define STAGE_A(slot, mh, kt) do {                                            \
  _Pragma("unroll") for (int j_ = 0; j_ < 2; ++j_)                            \
    __builtin_amdgcn_global_load_lds(                                         \
        GLB_SRC(pA + (long)(j_ * 128 + (mh) * 64) * K + (kt)),                \
        LDS_DST(smem + (slot) * 65536 + (arow0 + j_ * 128 + (mh) * 64) * 128),\
        16, 0, 0);                                                            \
} while (0)

#define STAGE_B(slot, nh, kt) do {                                            \
  _Pragma("unroll") for (int j_ = 0; j_ < 2; ++j_)                            \
    __builtin_amdgcn_global_load_lds(                                         \
        GLB_SRC(pB + (long)(j_ * 128 + (nh) * 32) * K + (kt)),                \
        LDS_DST(smem + (slot) * 65536 + 32768 +                               \
                (brow0 + j_ * 128 + (nh) * 32) * 128),                        \
        16, 0, 0);                                                            \
} while (0)

// write acc round RD (compile-time) into chunk buffer eb (64 rows x 256 cols)
#define EWRITE(RD, eb) do {                                                   \
  _Pragma("unroll") for (int fi = 0; fi < 2; ++fi)                            \
  _Pragma("unroll") for (int nf = 0; nf < 4; ++nf)                            \
  _Pragma("unroll") for (int r = 0; r < 4; ++r) {                             \
    const int lr2 = wr * 32 + fi * 16 + lg * 4 + r;                           \
    (eb)[lr2 * 256 + wc * 64 + nf * 16 + l15] = acc[(RD) * 2 + fi][nf][r];    \
  }                                                                           \
} while (0)

// MODE 0: bf16 out = acc + bias[n] (z=1 uses alt pointer set A2/B2/bias2/C2)
// MODE 1: bf16 out = mask ? sigmoid(acc) : 0 (mask read int32, direct)
// MODE 2: f32 out = acc
template <int MODE>
__global__ void __launch_bounds__(512, 2)
gemm8p_kernel(const bf16_t* __restrict__ A, const bf16_t* __restrict__ B,
              const float* __restrict__ bias, const int* __restrict__ mask,
              void* __restrict__ Cout, int M, int N, int K,
              long sA, long sB, long sC, long sMask,
              const bf16_t* __restrict__ A2, const bf16_t* __restrict__ B2,
              const float* __restrict__ bias2, void* __restrict__ C2) {
  __shared__ __align__(1024) char smem[131072];

  // ---- bijective XCD chunking (m204) + supertile decode (R9) ----
  const int gx = gridDim.x, gy = gridDim.y;
  int f0 = blockIdx.x + gx * (blockIdx.y + gy * blockIdx.z);
  const int nwg = gx * gy * (int)gridDim.z;
  const int q8 = nwg >> 3, r8 = nwg & 7;
  const int xcd = f0 & 7, idx = f0 >> 3;
  int f1 = (xcd < r8 ? xcd * (q8 + 1) : r8 * (q8 + 1) + (xcd - r8) * q8) + idx;
  int bxi, byi, bz;
  if constexpr (MODE == 1) {
    // supertile = 8bx x 2by; f1 = bx + 8*(by&1) + 16*((by>>1) + 4*bz)
    bxi = f1 & 7;
    const int byL = (f1 >> 3) & 1;
    const int st = (f1 >> 4) & 3;
    bz = f1 >> 6;
    byi = st * 2 + byL;
  } else {
    // by-major: f1 = by + gy*(bx + gx*bz)
    byi = f1 % gy;
    const int t = f1 / gy;
    bxi = t % gx;
    bz = t / gx;
  }

  const bf16_t* Ab; const bf16_t* Bb;
  const float* biasp = bias; void* Cp = Cout;
  if constexpr (MODE == 0) {
    if (bz) { Ab = A2; Bb = B2; biasp = bias2; Cp = C2; }
    else    { Ab = A;  Bb = B; }
  } else {
    Ab = A + bz * sA; Bb = B + bz * sB;
  }
  const int bm = bxi * 256, bn = byi * 256;
  const int tid = threadIdx.x;
  const int wave = tid >> 6, lane = tid & 63;
  const int wr = wave >> 2, wc = wave & 3;
  const int l15 = lane & 15, lg = lane >> 4;
  const int xk0 = (lg * 16) ^ ((lane & 7) << 4);
  const int NT = K >> 6;

  // staging bases
  const int lr = lane >> 3;
  const int cgs = ((lane & 7) ^ lr) * 8;
  const int arow0 = wave * 8;
  const int brow0 = (wave >> 2) * 64 + (wave & 3) * 8;
  const bf16_t* pA = Ab + (long)(bm + arow0 + lr) * K + cgs;
  const bf16_t* pB = Bb + (long)(bn + brow0 + lr) * K + cgs;

  // ds_read base offsets
  const int aoff = wr * 16384 + l15 * 128;          // + slot*65536 + mh*8192
  const int boff = 32768 + wc * 8192 + l15 * 128;   // + slot*65536 + nh*4096

  f32x4 acc[8][4] = {};
  bf16x8 afX[8], bfB[4], bf0[4];

  // ---- prologue: t0 full (8 instrs), then A0/B0(1) (4), B1/A1(1) (4) ----
  STAGE_A(0, 0, 0); STAGE_B(0, 0, 0); STAGE_B(0, 1, 0); STAGE_A(0, 1, 0);
  STAGE_A(1, 0, 64); STAGE_B(1, 0, 64);
  STAGE_B(1, 1, 64); STAGE_A(1, 1, 64);
  WVM8();   // tile0's 8 instrs landed
  SBAR();
  read_A(smem, aoff + 0, afX, xk0);   // A0(t0)
  read_B(smem, boff + 0, bf0, xk0);   // B0(t0)

  int slot = 0;
  for (int t = 0; t + 2 < NT; ++t) {
    const int so = slot * 65536, sn = (slot ^ 1) * 65536;
    const int k2 = (t + 2) << 6;
    // ---- P_a ----
    read_B(smem, so + boff + 4096, bfB, xk0);        // B1(t)
    STAGE_A(slot, 0, k2); STAGE_B(slot, 0, k2);      // A0(t+2), B0(t+2)
    SP1(); mfma_q<0, 0>(afX, bf0, acc); SP0();
    SP1(); mfma_q<0, 1>(afX, bfB, acc); SP0();
    read_A(smem, so + aoff + 8192, afX, xk0);        // A1(t)
    WVM8(); SBAR();                                  // c1
    // ---- P_b ----
    SP1(); mfma_q<1, 1>(afX, bfB, acc); SP0();
    SP1(); mfma_q<1, 0>(afX, bf0, acc); SP0();
    read_A(smem, sn + aoff + 0, afX, xk0);           // A0(t+1)
    read_B(smem, sn + boff + 0, bf0, xk0);           // B0(t+1)
    STAGE_B(slot, 1, k2); STAGE_A(slot, 1, k2);      // B1(t+2), A1(t+2)
    WVM8(); SBAR();                                  // c2
    slot ^= 1;
  }

  // ---- drain: tiles NT-2 (so), NT-1 (sn); no staging ----
  {
    const int so = slot * 65536, sn = (slot ^ 1) * 65536;
    read_B(smem, so + boff + 4096, bfB, xk0);        // B1(NT-2)
    SP1(); mfma_q<0, 0>(afX, bf0, acc); SP0();
    SP1(); mfma_q<0, 1>(afX, bfB, acc); SP0();
    read_A(smem, so + aoff + 8192, afX, xk0);        // A1(NT-2)
    WVM4(); SBAR();
    SP1(); mfma_q<1, 1>(afX, bfB, acc); SP0();
    SP1(); mfma_q<1, 0>(afX, bf0, acc); SP0();
    read_A(smem, sn + aoff + 0, afX, xk0);           // A0(NT-1)
    read_B(smem, sn + boff + 0, bf0, xk0);           // B0(NT-1)
    WVM0(); SBAR();
    // last tile
    read_B(smem, sn + boff + 4096, bfB, xk0);        // B1(NT-1)
    SP1(); mfma_q<0, 0>(afX, bf0, acc); SP0();
    SP1(); mfma_q<0, 1>(afX, bfB, acc); SP0();
    read_A(smem, sn + aoff + 8192, afX, xk0);        // A1(NT-1)
    SP1(); mfma_q<1, 1>(afX, bfB, acc); SP0();
    SP1(); mfma_q<1, 0>(afX, bf0, acc); SP0();
  }

  // ---- C-write: 4 rounds, double-buffered 64KB chunks, 1 barrier/round ----
  // (fully unrolled: acc/mask indices compile-time -- rule #20)
  float* eb0 = (float*)smem;
  float* eb1 = (float*)(smem + 65536);
  const int lrow = tid >> 3, t7 = tid & 7;
  const int growt0 = lrow + ((lrow >> 5) * 96);      // row map (wr0|wr1 halves)
  int4 m4a[8], m4b[8];
  if constexpr (MODE == 1) {
    const int* mrow = mask + bz * sMask + (long)(bm + growt0) * N + bn;
#pragma unroll
    for (int q = 0; q < 8; ++q)
      m4a[q] = *reinterpret_cast<const int4*>(mrow + (q * 8 + t7) * 4);
  }
  EWRITE(0, eb0);
  __syncthreads();
#pragma unroll
  for (int rd = 0; rd < 4; ++rd) {
    // prefetch next round's mask (uses the buffer NOT consumed this round)
    if constexpr (MODE == 1) {
      if (rd < 3) {
        const int* mrow =
            mask + bz * sMask + (long)(bm + (rd + 1) * 32 + growt0) * N + bn;
        if ((rd & 1) == 0) {
#pragma unroll
          for (int q = 0; q < 8; ++q)
            m4b[q] = *reinterpret_cast<const int4*>(mrow + (q * 8 + t7) * 4);
        } else {
#pragma unroll
          for (int q = 0; q < 8; ++q)
            m4a[q] = *reinterpret_cast<const int4*>(mrow + (q * 8 + t7) * 4);
        }
      }
    }
    // stage next round's acc into the other buffer (overlaps with emission)
    if (rd < 3) {
      if ((rd & 1) == 0) { EWRITE(rd + 1, eb1); } else { EWRITE(rd + 1, eb0); }
    }
    // emit this round from its buffer
    const float* eb = ((rd & 1) == 0) ? eb0 : eb1;
    const long rowbase = (long)(bm + rd * 32 + growt0) * N + bn;
#pragma unroll
    for (int q = 0; q < 8; ++q) {
      const int c4 = (q * 8 + t7) * 4;
      const f32x4 v = *reinterpret_cast<const f32x4*>(&eb[lrow * 256 + c4]);
      if constexpr (MODE == 1) {
        const int4 mq = ((rd & 1) == 0) ? m4a[q] : m4b[q];
        bf16x4 o;
        o[0] = (bf16_t)(mq.x ? __builtin_amdgcn_rcpf(1.f + __expf(-v[0])) : 0.f);
        o[1] = (bf16_t)(mq.y ? __builtin_amdgcn_rcpf(1.f + __expf(-v[1])) : 0.f);
        o[2] = (bf16_t)(mq.z ? __builtin_amdgcn_rcpf(1.f + __expf(-v[2])) : 0.f);
        o[3] = (bf16_t)(mq.w ? __builtin_amdgcn_rcpf(1.f + __expf(-v[3])) : 0.f);
        *reinterpret_cast<bf16x4*>((bf16_t*)Cp + bz * sC + rowbase + c4) = o;
      } else if constexpr (MODE == 0) {
        const f32x4 b4 = *reinterpret_cast<const f32x4*>(biasp + bn + c4);
        bf16x4 o;
        o[0] = (bf16_t)(v[0] + b4[0]); o[1] = (bf16_t)(v[1] + b4[1]);
        o[2] = (bf16_t)(v[2] + b4[2]); o[3] = (bf16_t)(v[3] + b4[3]);
        *reinterpret_cast<bf16x4*>((bf16_t*)Cp + bz * sC + rowbase + c4) = o;
      } else {
        *reinterpret_cast<f32x4*>((float*)Cp + bz * sC + rowbase + c4) = v;
      }
    }
    __syncthreads();   // protects: reads of this buffer done before rd+2 write
  }
}

extern "C" void kernel_launch(void* const* d_in, const int* in_sizes, int n_in,
                              void* d_out, int out_size, void* d_ws, size_t ws_size,
                              hipStream_t stream) {
  const float* queries = (const float*)d_in[0];
  const float* values  = (const float*)d_in[1];
  const int*   mask    = (const int*)d_in[2];
  const float* Wq = (const float*)d_in[3];
  const float* bq = (const float*)d_in[4];
  const float* Wk = (const float*)d_in[5];
  const float* bk = (const float*)d_in[6];
  const float* Wv = (const float*)d_in[7];
  const float* bv = (const float*)d_in[8];

  // B=8, L=2048, D=768. Workspace layout (bytes):
  char* ws = (char*)d_ws;
  bf16_t* qb  = (bf16_t*)(ws + 0);          // queries bf16   25165824
  bf16_t* vb  = (bf16_t*)(ws + 25165824);   // values bf16    25165824
  bf16_t* wqb = (bf16_t*)(ws + 50331648);   // Wq bf16         1179648
  bf16_t* wkb = (bf16_t*)(ws + 51511296);   // Wk bf16         1179648
  bf16_t* wvb = (bf16_t*)(ws + 52690944);   // Wv bf16         1179648
  bf16_t* qp  = (bf16_t*)(ws + 53870592);   // q_proj         25165824
  bf16_t* vp  = (bf16_t*)(ws + 79036416);   // v_proj         25165824
  bf16_t* kp  = (bf16_t*)(ws + 104202240);  // k_proj         25165824
  bf16_t* vpT = (bf16_t*)(ws + 129368064);  // v_proj^T       25165824
  bf16_t* P   = (bf16_t*)(ws + 154533888);  // sigmoid scores 67108864
  // total: 221642752

  // converts (q, v, 3 weights) in one launch, 4 float4/thread
  convert_kernel<<<6576, 256, 0, stream>>>(queries, values, Wq, Wk, Wv,
                                           qb, vb, wqb, wkb, wvb);

  const dim3 blk2(512);

  // q-proj & v-proj batched (independent): z=0 qb*Wq+bq->qp, z=1 vb*Wv+bv->vp
  gemm8p_kernel<0><<<dim3(64, 3, 2), blk2, 0, stream>>>(
      qb, wqb, bq, nullptr, qp, 16384, 768, 768, 0, 0, 0, 0,
      vb, wvb, bv, vp);
  // k-proj (faithful quirk: k = Linear_k(v_proj))
  gemm8p_kernel<0><<<dim3(64, 3, 1), blk2, 0, stream>>>(
      vp, wkb, bk, nullptr, kp, 16384, 768, 768, 0, 0, 0, 0,
      vp, wkb, bk, kp);

  // v_proj [b][2048][768] -> v_projT [b][768][2048]
  transpose_bf16_kernel<<<dim3(32, 12, 8), 256, 0, stream>>>(vp, vpT, 2048, 768);

  // P = sigmoid(mask(q k^T)) : per batch [2048,2048], K=768; int32 mask direct
  gemm8p_kernel<1><<<dim3(8, 8, 8), blk2, 0, stream>>>(
      qp, kp, nullptr, mask, P, 2048, 2048, 768,
      (long)2048 * 768, (long)2048 * 768, (long)2048 * 2048, (long)2048 * 2048,
      nullptr, nullptr, nullptr, nullptr);

  // context = P v : per batch [2048,768], K=2048, fp32 out
  gemm8p_kernel<2><<<dim3(8, 3, 8), blk2, 0, stream>>>(
      P, vpT, nullptr, nullptr, d_out, 2048, 768, 2048,
      (long)2048 * 2048, (long)768 * 2048, (long)2048 * 768, 0,
      nullptr, nullptr, nullptr, nullptr);
}